// Round 5
// baseline (3534.607 us; speedup 1.0000x reference)
//
#include <hip/hip_runtime.h>
#include <math.h>

// FusionEncoder: E=1024, F=4096, N=64 docs, L=2 layers, fp32.
// R5: megakernel with PLAIN launch + hand-rolled device-scope global barrier.
// R4's hipLaunchCooperativeKernel never ran (out stayed zero -> absmax ==
// max|ref|); cooperative validation likely rejected 512 blocks. Plain launch
// + __launch_bounds__(256,2) guarantees co-residency (VGPR<=256 -> >=2
// blocks/CU; LDS 34.8KB*2 <= 160KB), barrier via device-scope atomics.

#define EDIM 1024
#define FDIM 4096
#define NGRID 512   // 2 blocks/CU on 256 CUs; co-resident by launch_bounds

struct Params {
  const float *q, *doc, *Wp, *bp, *Wqkv, *bqkv, *Wo, *bo;
  const float *ln1g, *ln1b, *ln2g, *ln2b;
  const float *W1, *b1, *W2, *b2, *Wa1, *ba1, *Wa2, *ba2;
  const float *Wf1, *bf1, *Wf2, *bf2;
  float *out;
  float *x, *vbuf, *h, *P, *P2, *logits, *fused, *g;
  int *bar;   // [0]=arrival count, [1]=generation (memset to 0 per call)
};

// ---- grid-wide barrier: epoch counter + device-scope atomics ---------------
__device__ __forceinline__ void gbar(int* bar, int nb) {
  __threadfence();                      // flush my block's writes device-wide
  __syncthreads();
  if (threadIdx.x == 0) {
    const int g = __hip_atomic_load(bar + 1, __ATOMIC_RELAXED, __HIP_MEMORY_SCOPE_AGENT);
    const int prev = __hip_atomic_fetch_add(bar + 0, 1, __ATOMIC_ACQ_REL, __HIP_MEMORY_SCOPE_AGENT);
    if (prev == nb - 1) {
      __hip_atomic_store(bar + 0, 0, __ATOMIC_RELAXED, __HIP_MEMORY_SCOPE_AGENT);
      __hip_atomic_fetch_add(bar + 1, 1, __ATOMIC_RELEASE, __HIP_MEMORY_SCOPE_AGENT);
    } else {
      long spins = 0;
      while (__hip_atomic_load(bar + 1, __ATOMIC_ACQUIRE, __HIP_MEMORY_SCOPE_AGENT) == g) {
        __builtin_amdgcn_s_sleep(4);
        if (++spins > (1L << 26)) break;   // deadlock fuse; never fires healthy
      }
    }
  }
  __syncthreads();
  __threadfence();                      // invalidate stale L1 before reads
}

// ---------------- block-wide sum over 256 threads (4 waves) ----------------
__device__ __forceinline__ float block_sum256(float v) {
  __shared__ float lds[4];
  #pragma unroll
  for (int off = 32; off; off >>= 1) v += __shfl_down(v, off);
  const int wid  = threadIdx.x >> 6;
  const int lane = threadIdx.x & 63;
  __syncthreads();
  if (lane == 0) lds[wid] = v;
  __syncthreads();
  return lds[0] + lds[1] + lds[2] + lds[3];
}

#define FMA4(ACC, S, W4) \
  ACC.x = fmaf(S, W4.x, ACC.x); ACC.y = fmaf(S, W4.y, ACC.y); \
  ACC.z = fmaf(S, W4.z, ACC.z); ACC.w = fmaf(S, W4.w, ACC.w);

// ---- one 64x64 output tile over K range [kb, kb+Kt); A & W staged in LDS ---
template<int MODE_A>
__device__ __forceinline__ void gemm_tile(
    const float* __restrict__ A, int lda,
    const float* __restrict__ qv, const float* __restrict__ doc,
    const float* __restrict__ W, int ldw,
    float* __restrict__ Pout, int Nout, int jb, int kb, int Kt,
    float* As, float* Ws)
{
  const int t   = threadIdx.x;
  const int cgi = t & 15;
  const int r0  = (t >> 4) * 4;
  const int jc  = jb + cgi * 4;

  float4 acc[4];
  #pragma unroll
  for (int i = 0; i < 4; ++i) acc[i] = make_float4(0.f, 0.f, 0.f, 0.f);

  for (int k0 = kb; k0 < kb + Kt; k0 += 64) {
    __syncthreads();
    #pragma unroll
    for (int it = 0; it < 4; ++it) {               // stage A[0..63][k0+0..63]
      const int pi  = t + it * 256;
      const int row = pi >> 4;
      const int c4  = (pi & 15) * 4;
      const int k   = k0 + c4;
      float4 val;
      if (MODE_A == 1)
        val = (k < EDIM) ? *(const float4*)(qv + k)
                         : *(const float4*)(doc + (size_t)row * EDIM + (k - EDIM));
      else
        val = *(const float4*)(A + (size_t)row * lda + k);
      *(float4*)(As + row * 68 + c4) = val;
    }
    #pragma unroll
    for (int it = 0; it < 4; ++it) {               // stage W[k0+0..63][jb+0..63]
      const int pi  = t + it * 256;
      const int row = pi >> 4;
      const int c4  = (pi & 15) * 4;
      *(float4*)(Ws + row * 68 + c4) =
          *(const float4*)(W + (size_t)(k0 + row) * ldw + jb + c4);
    }
    __syncthreads();
    #pragma unroll 4
    for (int kk4 = 0; kk4 < 64; kk4 += 4) {
      const float4 a0 = *(const float4*)(As + (r0 + 0) * 68 + kk4);
      const float4 a1 = *(const float4*)(As + (r0 + 1) * 68 + kk4);
      const float4 a2 = *(const float4*)(As + (r0 + 2) * 68 + kk4);
      const float4 a3 = *(const float4*)(As + (r0 + 3) * 68 + kk4);
      const float4 w0 = *(const float4*)(Ws + (kk4 + 0) * 68 + cgi * 4);
      const float4 w1 = *(const float4*)(Ws + (kk4 + 1) * 68 + cgi * 4);
      const float4 w2 = *(const float4*)(Ws + (kk4 + 2) * 68 + cgi * 4);
      const float4 w3 = *(const float4*)(Ws + (kk4 + 3) * 68 + cgi * 4);
      FMA4(acc[0], a0.x, w0) FMA4(acc[0], a0.y, w1) FMA4(acc[0], a0.z, w2) FMA4(acc[0], a0.w, w3)
      FMA4(acc[1], a1.x, w0) FMA4(acc[1], a1.y, w1) FMA4(acc[1], a1.z, w2) FMA4(acc[1], a1.w, w3)
      FMA4(acc[2], a2.x, w0) FMA4(acc[2], a2.y, w1) FMA4(acc[2], a2.z, w2) FMA4(acc[2], a2.w, w3)
      FMA4(acc[3], a3.x, w0) FMA4(acc[3], a3.y, w1) FMA4(acc[3], a3.z, w2) FMA4(acc[3], a3.w, w3)
    }
  }
  #pragma unroll
  for (int i = 0; i < 4; ++i)
    *(float4*)(Pout + (size_t)(r0 + i) * Nout + jc) = acc[i];
}

// ---- split-K reduce (+bias, +residual, +LN) for 64x1024; blocks >=64 idle --
__device__ __forceinline__ void reduce_row(
    const float* __restrict__ P, int S, const float* __restrict__ bias,
    const float* __restrict__ res, const float* __restrict__ gam,
    const float* __restrict__ bet, float* __restrict__ outp, int LN)
{
  const int row = blockIdx.x;
  if (row >= 64) return;
  const int c = threadIdx.x * 4;
  float4 v = make_float4(0.f, 0.f, 0.f, 0.f);
  for (int s = 0; s < S; ++s) {
    const float4 pp = *(const float4*)(P + ((size_t)s * 64 + row) * EDIM + c);
    v.x += pp.x; v.y += pp.y; v.z += pp.z; v.w += pp.w;
  }
  const float4 b4 = *(const float4*)(bias + c);
  v.x += b4.x; v.y += b4.y; v.z += b4.z; v.w += b4.w;
  if (res) {
    const float4 r4 = *(const float4*)(res + (size_t)row * EDIM + c);
    v.x += r4.x; v.y += r4.y; v.z += r4.z; v.w += r4.w;
  }
  if (LN) {
    const float mean = block_sum256(v.x + v.y + v.z + v.w) * (1.f / 1024.f);
    const float dx = v.x - mean, dy = v.y - mean, dz = v.z - mean, dw = v.w - mean;
    const float var = block_sum256(dx * dx + dy * dy + dz * dz + dw * dw) * (1.f / 1024.f);
    const float inv = 1.f / sqrtf(var + 1e-5f);
    const float4 g4 = *(const float4*)(gam + c);
    const float4 l4 = *(const float4*)(bet + c);
    v.x = dx * inv * g4.x + l4.x;
    v.y = dy * inv * g4.y + l4.y;
    v.z = dz * inv * g4.z + l4.z;
    v.w = dw * inv * g4.w + l4.w;
  }
  *(float4*)(outp + (size_t)row * EDIM + c) = v;
}

// ---------------------------------------------------------------------------
__global__ __launch_bounds__(256, 2) void mega_k(Params p) {
  __shared__ float As[64 * 68];
  __shared__ float Ws[64 * 68];
  const int bx = blockIdx.x;
  const int t  = threadIdx.x;
  int* bar = p.bar;

  // ---- proj: x = concat(q,doc) @ Wp + bp (K=2048, 16 tiles x S=32, Kt=64)
  { const int s = bx >> 4;
    if (s < 32) gemm_tile<1>(p.x, 0, p.q, p.doc, p.Wp, EDIM,
                             p.P + (size_t)s * 64 * EDIM, EDIM, (bx & 15) * 64, s * 64, 64, As, Ws); }
  gbar(bar, NGRID);
  reduce_row(p.P, 32, p.bp, nullptr, nullptr, nullptr, p.x, 0);
  gbar(bar, NGRID);

  for (int l = 0; l < 2; ++l) {
    const float* Wv  = p.Wqkv + (size_t)l * EDIM * 3 * EDIM + 2 * EDIM;
    const float* bv  = p.bqkv + l * 3 * EDIM + 2 * EDIM;
    const float* Wol = p.Wo + (size_t)l * EDIM * EDIM;
    const float* W1l = p.W1 + (size_t)l * EDIM * FDIM;
    const float* W2l = p.W2 + (size_t)l * FDIM * EDIM;

    // v = x @ Wv + bv   (16 tiles x S=16, Kt=64)
    { const int s = bx >> 4;
      if (s < 16) gemm_tile<0>(p.x, EDIM, nullptr, nullptr, Wv, 3 * EDIM,
                               p.P + (size_t)s * 64 * EDIM, EDIM, (bx & 15) * 64, s * 64, 64, As, Ws); }
    gbar(bar, NGRID);
    reduce_row(p.P, 16, bv, nullptr, nullptr, nullptr, p.vbuf, 0);
    gbar(bar, NGRID);

    // attn = v @ Wo + bo ; x = LN1(x + attn)
    { const int s = bx >> 4;
      if (s < 16) gemm_tile<0>(p.vbuf, EDIM, nullptr, nullptr, Wol, EDIM,
                               p.P + (size_t)s * 64 * EDIM, EDIM, (bx & 15) * 64, s * 64, 64, As, Ws); }
    gbar(bar, NGRID);
    reduce_row(p.P, 16, p.bo + l * EDIM, p.x, p.ln1g + l * EDIM, p.ln1b + l * EDIM, p.x, 1);
    gbar(bar, NGRID);

    // h = relu(x @ W1 + b1)   (64 tiles x S=8, Kt=128)
    { const int s = bx >> 6;
      if (s < 8) gemm_tile<0>(p.x, EDIM, nullptr, nullptr, W1l, FDIM,
                              p.P + (size_t)s * 64 * FDIM, FDIM, (bx & 63) * 64, s * 128, 128, As, Ws); }
    gbar(bar, NGRID);
    if (bx < 256) {
      const int flat = (bx * 256 + t) * 4;
      const int col  = flat & (FDIM - 1);
      float4 v = make_float4(0.f, 0.f, 0.f, 0.f);
      for (int s = 0; s < 8; ++s) {
        const float4 pp = *(const float4*)(p.P + (size_t)s * 64 * FDIM + flat);
        v.x += pp.x; v.y += pp.y; v.z += pp.z; v.w += pp.w;
      }
      const float4 b4 = *(const float4*)(p.b1 + l * FDIM + col);
      v.x = fmaxf(v.x + b4.x, 0.f); v.y = fmaxf(v.y + b4.y, 0.f);
      v.z = fmaxf(v.z + b4.z, 0.f); v.w = fmaxf(v.w + b4.w, 0.f);
      *(float4*)(p.h + flat) = v;
    }
    gbar(bar, NGRID);

    // x = LN2(x + h @ W2 + b2)   (16 tiles x S=32, Kt=128, K=4096)
    { const int s = bx >> 4;
      if (s < 32) gemm_tile<0>(p.h, FDIM, nullptr, nullptr, W2l, EDIM,
                               p.P + (size_t)s * 64 * EDIM, EDIM, (bx & 15) * 64, s * 128, 128, As, Ws); }
    gbar(bar, NGRID);
    reduce_row(p.P, 32, p.b2 + l * EDIM, p.x, p.ln2g + l * EDIM, p.ln2b + l * EDIM, p.x, 1);
    gbar(bar, NGRID);
  }

  // ---- head: wa1 gemm (64 tiles x S=8, Kt=128); 'a' never materialized
  { const int s = bx >> 6;
    if (s < 8) gemm_tile<0>(p.x, EDIM, nullptr, nullptr, p.Wa1, FDIM,
                            p.P + (size_t)s * 64 * FDIM, FDIM, (bx & 63) * 64, s * 128, 128, As, Ws); }
  gbar(bar, NGRID);
  // fused reduce(+ba1+relu) and logits[row] = dot(a_row, Wa2) + ba2
  if (bx < 64) {
    const int row = bx;
    float dot = 0.f;
    #pragma unroll
    for (int i = 0; i < 4; ++i) {
      const int col = (t + i * 256) * 4;
      float4 v = make_float4(0.f, 0.f, 0.f, 0.f);
      for (int s = 0; s < 8; ++s) {
        const float4 pp = *(const float4*)(p.P + ((size_t)s * 64 + row) * FDIM + col);
        v.x += pp.x; v.y += pp.y; v.z += pp.z; v.w += pp.w;
      }
      const float4 b4 = *(const float4*)(p.ba1 + col);
      v.x = fmaxf(v.x + b4.x, 0.f); v.y = fmaxf(v.y + b4.y, 0.f);
      v.z = fmaxf(v.z + b4.z, 0.f); v.w = fmaxf(v.w + b4.w, 0.f);
      const float4 w2 = *(const float4*)(p.Wa2 + col);
      dot = fmaf(v.x, w2.x, fmaf(v.y, w2.y, fmaf(v.z, w2.z, fmaf(v.w, w2.w, dot))));
    }
    const float ssum = block_sum256(dot);
    if (t == 0) p.logits[row] = ssum + p.ba2[0];
  }
  gbar(bar, NGRID);
  // softmax over 64 + weighted pool; block 0 writes w to out[FDIM..]
  if (bx < 4) {
    __shared__ float ll[64];
    __shared__ float wl[64];
    if (t < 64) ll[t] = p.logits[t];
    __syncthreads();
    float m = -1e30f;
    for (int i = 0; i < 64; ++i) m = fmaxf(m, ll[i]);
    float den = 0.f;
    for (int i = 0; i < 64; ++i) den += expf(ll[i] - m);
    if (t < 64) wl[t] = expf(ll[t] - m) / den;
    __syncthreads();
    const int j = bx * 256 + t;
    float acc = 0.f;
    for (int i = 0; i < 64; ++i) acc = fmaf(wl[i], p.x[(size_t)i * EDIM + j], acc);
    p.fused[j] = acc;
    if (bx == 0 && t < 64) p.out[FDIM + t] = wl[t];
  }
  gbar(bar, NGRID);

  // ---- gemv1: g = relu(fused @ Wf1 + bf1)  (16 colgrps x S=32, Kt=32)
  { const int cgi = bx & 15, s = bx >> 4;
    if (s < 32) {
      const int k0 = s * 32;
      if (t < 32) As[t] = p.fused[k0 + t];
      __syncthreads();
      const int col = cgi * 256 + t;
      const float* wp = p.Wf1 + (size_t)k0 * FDIM + col;
      float acc = 0.f;
      #pragma unroll
      for (int kk = 0; kk < 32; ++kk) acc = fmaf(As[kk], wp[(size_t)kk * FDIM], acc);
      p.P[(size_t)s * FDIM + col] = acc;
    } }
  gbar(bar, NGRID);
  if (bx < 16) {
    const int col = bx * 256 + t;
    float v = 0.f;
    for (int s = 0; s < 32; ++s) v += p.P[(size_t)s * FDIM + col];
    p.g[col] = fmaxf(v + p.bf1[col], 0.f);
  }
  gbar(bar, NGRID);

  // ---- gemv2: out = g @ Wf2 + bf2  (16 colgrps x S=32, Kt=128)
  { const int cgi = bx & 15, s = bx >> 4;
    if (s < 32) {
      const int k0 = s * 128;
      if (t < 128) As[t] = p.g[k0 + t];
      __syncthreads();
      const int col = cgi * 256 + t;
      const float* wp = p.Wf2 + (size_t)k0 * FDIM + col;
      float acc = 0.f;
      #pragma unroll 16
      for (int kk = 0; kk < 128; ++kk) acc = fmaf(As[kk], wp[(size_t)kk * FDIM], acc);
      p.P2[(size_t)s * FDIM + col] = acc;
    } }
  gbar(bar, NGRID);
  if (bx < 16) {
    const int col = bx * 256 + t;
    float v = 0.f;
    for (int s = 0; s < 32; ++s) v += p.P2[(size_t)s * FDIM + col];
    p.out[col] = v + p.bf2[col];
  }
}

// ---------------------------------------------------------------------------
extern "C" void kernel_launch(void* const* d_in, const int* in_sizes, int n_in,
                              void* d_out, int out_size, void* d_ws, size_t ws_size,
                              hipStream_t stream) {
  (void)in_sizes; (void)n_in; (void)out_size; (void)ws_size;
  float* ws = (float*)d_ws;

  Params p;
  p.q    = (const float*)d_in[0];   p.doc  = (const float*)d_in[1];
  p.Wp   = (const float*)d_in[2];   p.bp   = (const float*)d_in[3];
  p.Wqkv = (const float*)d_in[4];   p.bqkv = (const float*)d_in[5];
  p.Wo   = (const float*)d_in[6];   p.bo   = (const float*)d_in[7];
  p.ln1g = (const float*)d_in[8];   p.ln1b = (const float*)d_in[9];
  p.ln2g = (const float*)d_in[10];  p.ln2b = (const float*)d_in[11];
  p.W1   = (const float*)d_in[12];  p.b1   = (const float*)d_in[13];
  p.W2   = (const float*)d_in[14];  p.b2   = (const float*)d_in[15];
  p.Wa1  = (const float*)d_in[16];  p.ba1  = (const float*)d_in[17];
  p.Wa2  = (const float*)d_in[18];  p.ba2  = (const float*)d_in[19];
  p.Wf1  = (const float*)d_in[20];  p.bf1  = (const float*)d_in[21];
  p.Wf2  = (const float*)d_in[22];  p.bf2  = (const float*)d_in[23];
  p.out  = (float*)d_out;

  // workspace layout (floats)
  p.x      = ws;                      // 64x1024
  p.vbuf   = ws + 65536;              // 64x1024
  p.h      = ws + 131072;             // 64x4096
  p.P      = ws + 655360;             // 2M floats: gemm partials / gemv1 partials
  p.P2     = ws + 655360 + 262144;    // 32x4096 gemv2 partials
  p.logits = ws + 2752512;            // 64
  p.fused  = ws + 2752576;            // 1024
  p.g      = ws + 2753600;            // 4096
  p.bar    = (int*)(ws + 2757696);    // 2 ints barrier state

  hipMemsetAsync(p.bar, 0, 64, stream);
  mega_k<<<dim3(NGRID), dim3(256), 0, stream>>>(p);
}

// Round 8
// 571.419 us; speedup vs baseline: 6.1857x; 6.1857x over previous
//
#include <hip/hip_runtime.h>
#include <math.h>

// FusionEncoder: E=1024, F=4096, N=64 docs, L=2 layers, fp32.
// R8: R5's DETERMINISTIC dataflow (per-block partial slots + fixed-order
// reduce; R7's float atomicAdd broke the replay-determinism tripwire) with
// R6/R7's fast tree barrier (leaf-sharded relaxed RMWs, one acquire fence).

#define EDIM 1024
#define FDIM 4096
#define NGRID 512   // 2 blocks/CU; co-resident via __launch_bounds__(256,2)

struct Params {
  const float *q, *doc, *Wp, *bp, *Wqkv, *bqkv, *Wo, *bo;
  const float *ln1g, *ln1b, *ln2g, *ln2b;
  const float *W1, *b1, *W2, *b2, *Wa1, *ba1, *Wa2, *ba2;
  const float *Wf1, *bf1, *Wf2, *bf2;
  float *out;
  float *x, *vbuf, *h, *P, *P2, *logits, *fused, *g;
  int *bar;   // 8 leaves @ li*64, root @ 512, gen @ 576; memset per call
};

// ---- grid barrier v2: monotonic tree, relaxed RMWs, one acquire at exit ----
__device__ __forceinline__ void gbar(int* B, int k) {
  __syncthreads();
  if (threadIdx.x == 0) {
    __builtin_amdgcn_fence(__ATOMIC_RELEASE, "agent");
    int* leaf = B + (blockIdx.x & 7) * 64;        // 256B apart
    int* root = B + 512;
    int* gen  = B + 576;
    const int prev = __hip_atomic_fetch_add(leaf, 1, __ATOMIC_RELAXED, __HIP_MEMORY_SCOPE_AGENT);
    if (prev == k * 64 - 1) {                     // last of my 64-block leaf
      const int rprev = __hip_atomic_fetch_add(root, 1, __ATOMIC_RELEASE, __HIP_MEMORY_SCOPE_AGENT);
      if (rprev == k * 8 - 1)                     // last leaf -> open barrier k
        __hip_atomic_fetch_add(gen, 1, __ATOMIC_RELEASE, __HIP_MEMORY_SCOPE_AGENT);
    }
    int spins = 0;
    while (__hip_atomic_load(gen, __ATOMIC_RELAXED, __HIP_MEMORY_SCOPE_AGENT) < k) {
      __builtin_amdgcn_s_sleep(16);               // backoff per poll
      if (++spins > (1 << 16)) break;             // fuse: fail fast, not hang
    }
    __builtin_amdgcn_fence(__ATOMIC_ACQUIRE, "agent");
  }
  __syncthreads();
}

// ---------------- block-wide sum over 256 threads (4 waves) ----------------
__device__ __forceinline__ float block_sum256(float v) {
  __shared__ float lds[4];
  #pragma unroll
  for (int off = 32; off; off >>= 1) v += __shfl_down(v, off);
  const int wid  = threadIdx.x >> 6;
  const int lane = threadIdx.x & 63;
  __syncthreads();
  if (lane == 0) lds[wid] = v;
  __syncthreads();
  return lds[0] + lds[1] + lds[2] + lds[3];
}

#define FMA4(ACC, S, W4) \
  ACC.x = fmaf(S, W4.x, ACC.x); ACC.y = fmaf(S, W4.y, ACC.y); \
  ACC.z = fmaf(S, W4.z, ACC.z); ACC.w = fmaf(S, W4.w, ACC.w);

// ---- 64x64 output tile over K range [kb,kb+Kt); A & W staged in LDS --------
// Deterministic: writes its own partial slot Pout (no atomics).
template<int MODE_A>
__device__ __forceinline__ void gemm_tile(
    const float* __restrict__ A, int lda,
    const float* __restrict__ qv, const float* __restrict__ doc,
    const float* __restrict__ W, int ldw,
    float* __restrict__ Pout, int Nout, int jb, int kb, int Kt,
    float* As, float* Ws)
{
  const int t   = threadIdx.x;
  const int cgi = t & 15;
  const int r0  = (t >> 4) * 4;
  const int jc  = jb + cgi * 4;

  float4 acc[4];
  #pragma unroll
  for (int i = 0; i < 4; ++i) acc[i] = make_float4(0.f, 0.f, 0.f, 0.f);

  for (int k0 = kb; k0 < kb + Kt; k0 += 64) {
    __syncthreads();
    #pragma unroll
    for (int it = 0; it < 4; ++it) {               // stage A[0..63][k0+0..63]
      const int pi  = t + it * 256;
      const int row = pi >> 4;
      const int c4  = (pi & 15) * 4;
      const int k   = k0 + c4;
      float4 val;
      if (MODE_A == 1)
        val = (k < EDIM) ? *(const float4*)(qv + k)
                         : *(const float4*)(doc + (size_t)row * EDIM + (k - EDIM));
      else
        val = *(const float4*)(A + (size_t)row * lda + k);
      *(float4*)(As + row * 68 + c4) = val;
    }
    #pragma unroll
    for (int it = 0; it < 4; ++it) {               // stage W[k0+0..63][jb+0..63]
      const int pi  = t + it * 256;
      const int row = pi >> 4;
      const int c4  = (pi & 15) * 4;
      *(float4*)(Ws + row * 68 + c4) =
          *(const float4*)(W + (size_t)(k0 + row) * ldw + jb + c4);
    }
    __syncthreads();
    #pragma unroll 4
    for (int kk4 = 0; kk4 < 64; kk4 += 4) {
      const float4 a0 = *(const float4*)(As + (r0 + 0) * 68 + kk4);
      const float4 a1 = *(const float4*)(As + (r0 + 1) * 68 + kk4);
      const float4 a2 = *(const float4*)(As + (r0 + 2) * 68 + kk4);
      const float4 a3 = *(const float4*)(As + (r0 + 3) * 68 + kk4);
      const float4 w0 = *(const float4*)(Ws + (kk4 + 0) * 68 + cgi * 4);
      const float4 w1 = *(const float4*)(Ws + (kk4 + 1) * 68 + cgi * 4);
      const float4 w2 = *(const float4*)(Ws + (kk4 + 2) * 68 + cgi * 4);
      const float4 w3 = *(const float4*)(Ws + (kk4 + 3) * 68 + cgi * 4);
      FMA4(acc[0], a0.x, w0) FMA4(acc[0], a0.y, w1) FMA4(acc[0], a0.z, w2) FMA4(acc[0], a0.w, w3)
      FMA4(acc[1], a1.x, w0) FMA4(acc[1], a1.y, w1) FMA4(acc[1], a1.z, w2) FMA4(acc[1], a1.w, w3)
      FMA4(acc[2], a2.x, w0) FMA4(acc[2], a2.y, w1) FMA4(acc[2], a2.z, w2) FMA4(acc[2], a2.w, w3)
      FMA4(acc[3], a3.x, w0) FMA4(acc[3], a3.y, w1) FMA4(acc[3], a3.z, w2) FMA4(acc[3], a3.w, w3)
    }
  }
  #pragma unroll
  for (int i = 0; i < 4; ++i)
    *(float4*)(Pout + (size_t)(r0 + i) * Nout + jc) = acc[i];
}

// ---- split-K reduce (+bias, +residual, +LN) for 64x1024 --------------------
__device__ __forceinline__ void reduce_row(
    const float* __restrict__ P, int S, const float* __restrict__ bias,
    const float* __restrict__ res, const float* __restrict__ gam,
    const float* __restrict__ bet, float* __restrict__ outp, int LN)
{
  const int row = blockIdx.x;
  if (row >= 64) return;
  const int c = threadIdx.x * 4;
  float4 v = make_float4(0.f, 0.f, 0.f, 0.f);
  for (int s = 0; s < S; ++s) {
    const float4 pp = *(const float4*)(P + ((size_t)s * 64 + row) * EDIM + c);
    v.x += pp.x; v.y += pp.y; v.z += pp.z; v.w += pp.w;
  }
  const float4 b4 = *(const float4*)(bias + c);
  v.x += b4.x; v.y += b4.y; v.z += b4.z; v.w += b4.w;
  if (res) {
    const float4 r4 = *(const float4*)(res + (size_t)row * EDIM + c);
    v.x += r4.x; v.y += r4.y; v.z += r4.z; v.w += r4.w;
  }
  if (LN) {
    const float mean = block_sum256(v.x + v.y + v.z + v.w) * (1.f / 1024.f);
    const float dx = v.x - mean, dy = v.y - mean, dz = v.z - mean, dw = v.w - mean;
    const float var = block_sum256(dx * dx + dy * dy + dz * dz + dw * dw) * (1.f / 1024.f);
    const float inv = 1.f / sqrtf(var + 1e-5f);
    const float4 g4 = *(const float4*)(gam + c);
    const float4 l4 = *(const float4*)(bet + c);
    v.x = dx * inv * g4.x + l4.x;
    v.y = dy * inv * g4.y + l4.y;
    v.z = dz * inv * g4.z + l4.z;
    v.w = dw * inv * g4.w + l4.w;
  }
  *(float4*)(outp + (size_t)row * EDIM + c) = v;
}

// ---------------------------------------------------------------------------
__global__ __launch_bounds__(256, 2) void mega_k(Params p) {
  __shared__ float As[64 * 68];
  __shared__ float Ws[64 * 68];
  const int bx = blockIdx.x;
  const int t  = threadIdx.x;
  int* bar = p.bar;
  int k = 0;

  // ---- proj: x = concat(q,doc) @ Wp + bp (16 col x 32 splits, Kt=64)
  { const int s = bx >> 4;
    if (s < 32) gemm_tile<1>(p.x, 0, p.q, p.doc, p.Wp, EDIM,
                             p.P + (size_t)s * 64 * EDIM, EDIM, (bx & 15) * 64, s * 64, 64, As, Ws); }
  gbar(bar, ++k);
  reduce_row(p.P, 32, p.bp, nullptr, nullptr, nullptr, p.x, 0);
  gbar(bar, ++k);

  for (int l = 0; l < 2; ++l) {
    const float* Wv  = p.Wqkv + (size_t)l * EDIM * 3 * EDIM + 2 * EDIM;
    const float* bv  = p.bqkv + l * 3 * EDIM + 2 * EDIM;
    const float* Wol = p.Wo + (size_t)l * EDIM * EDIM;
    const float* W1l = p.W1 + (size_t)l * EDIM * FDIM;
    const float* W2l = p.W2 + (size_t)l * FDIM * EDIM;

    // v = x @ Wv + bv   (16 col x 16 splits, Kt=64)
    { const int s = bx >> 4;
      if (s < 16) gemm_tile<0>(p.x, EDIM, nullptr, nullptr, Wv, 3 * EDIM,
                               p.P + (size_t)s * 64 * EDIM, EDIM, (bx & 15) * 64, s * 64, 64, As, Ws); }
    gbar(bar, ++k);
    reduce_row(p.P, 16, bv, nullptr, nullptr, nullptr, p.vbuf, 0);
    gbar(bar, ++k);

    // attn = v @ Wo ; x = LN1(x + attn + bo)
    { const int s = bx >> 4;
      if (s < 16) gemm_tile<0>(p.vbuf, EDIM, nullptr, nullptr, Wol, EDIM,
                               p.P + (size_t)s * 64 * EDIM, EDIM, (bx & 15) * 64, s * 64, 64, As, Ws); }
    gbar(bar, ++k);
    reduce_row(p.P, 16, p.bo + l * EDIM, p.x, p.ln1g + l * EDIM, p.ln1b + l * EDIM, p.x, 1);
    gbar(bar, ++k);

    // h = relu(x @ W1 + b1)   (64 col x 8 splits, Kt=128)
    { const int s = bx >> 6;
      if (s < 8) gemm_tile<0>(p.x, EDIM, nullptr, nullptr, W1l, FDIM,
                              p.P + (size_t)s * 64 * FDIM, FDIM, (bx & 63) * 64, s * 128, 128, As, Ws); }
    gbar(bar, ++k);
    if (bx < 256) {
      const int flat = (bx * 256 + t) * 4;
      const int col  = flat & (FDIM - 1);
      float4 v = make_float4(0.f, 0.f, 0.f, 0.f);
      for (int s = 0; s < 8; ++s) {
        const float4 pp = *(const float4*)(p.P + (size_t)s * 64 * FDIM + flat);
        v.x += pp.x; v.y += pp.y; v.z += pp.z; v.w += pp.w;
      }
      const float4 b4 = *(const float4*)(p.b1 + l * FDIM + col);
      v.x = fmaxf(v.x + b4.x, 0.f); v.y = fmaxf(v.y + b4.y, 0.f);
      v.z = fmaxf(v.z + b4.z, 0.f); v.w = fmaxf(v.w + b4.w, 0.f);
      *(float4*)(p.h + flat) = v;
    }
    gbar(bar, ++k);

    // x = LN2(x + h @ W2 + b2)   (16 col x 32 splits, Kt=128, K=4096)
    { const int s = bx >> 4;
      if (s < 32) gemm_tile<0>(p.h, FDIM, nullptr, nullptr, W2l, EDIM,
                               p.P + (size_t)s * 64 * EDIM, EDIM, (bx & 15) * 64, s * 128, 128, As, Ws); }
    gbar(bar, ++k);
    reduce_row(p.P, 32, p.b2 + l * EDIM, p.x, p.ln2g + l * EDIM, p.ln2b + l * EDIM, p.x, 1);
    gbar(bar, ++k);
  }

  // ---- head: wa1 gemm (64 col x 8 splits, Kt=128); 'a' never materialized
  { const int s = bx >> 6;
    if (s < 8) gemm_tile<0>(p.x, EDIM, nullptr, nullptr, p.Wa1, FDIM,
                            p.P + (size_t)s * 64 * FDIM, FDIM, (bx & 63) * 64, s * 128, 128, As, Ws); }
  gbar(bar, ++k);
  // fused reduce(+ba1+relu) and logits[row] = dot(a_row, Wa2) + ba2
  if (bx < 64) {
    const int row = bx;
    float dot = 0.f;
    #pragma unroll
    for (int i = 0; i < 4; ++i) {
      const int col = (t + i * 256) * 4;
      float4 v = make_float4(0.f, 0.f, 0.f, 0.f);
      for (int s = 0; s < 8; ++s) {
        const float4 pp = *(const float4*)(p.P + ((size_t)s * 64 + row) * FDIM + col);
        v.x += pp.x; v.y += pp.y; v.z += pp.z; v.w += pp.w;
      }
      const float4 b4 = *(const float4*)(p.ba1 + col);
      v.x = fmaxf(v.x + b4.x, 0.f); v.y = fmaxf(v.y + b4.y, 0.f);
      v.z = fmaxf(v.z + b4.z, 0.f); v.w = fmaxf(v.w + b4.w, 0.f);
      const float4 w2 = *(const float4*)(p.Wa2 + col);
      dot = fmaf(v.x, w2.x, fmaf(v.y, w2.y, fmaf(v.z, w2.z, fmaf(v.w, w2.w, dot))));
    }
    const float ssum = block_sum256(dot);
    if (t == 0) p.logits[row] = ssum + p.ba2[0];
  }
  gbar(bar, ++k);
  // softmax over 64 + weighted pool; block 0 writes w
  if (bx < 4) {
    __shared__ float ll[64];
    __shared__ float wl[64];
    if (t < 64) ll[t] = p.logits[t];
    __syncthreads();
    float m = -1e30f;
    for (int i = 0; i < 64; ++i) m = fmaxf(m, ll[i]);
    float den = 0.f;
    for (int i = 0; i < 64; ++i) den += expf(ll[i] - m);
    if (t < 64) wl[t] = expf(ll[t] - m) / den;
    __syncthreads();
    const int j = bx * 256 + t;
    float acc = 0.f;
    for (int i = 0; i < 64; ++i) acc = fmaf(wl[i], p.x[(size_t)i * EDIM + j], acc);
    p.fused[j] = acc;
    if (bx == 0 && t < 64) p.out[FDIM + t] = wl[t];
  }
  gbar(bar, ++k);

  // ---- gemv1: fused @ Wf1 partials  (16 colgrps x 32 splits, Kt=32)
  { const int s = bx >> 4;                 // 0..31
    const int k0 = s * 32;
    if (t < 32) As[t] = p.fused[k0 + t];
    __syncthreads();
    const int col = (bx & 15) * 256 + t;
    const float* wp = p.Wf1 + (size_t)k0 * FDIM + col;
    float acc = 0.f;
    #pragma unroll
    for (int kk = 0; kk < 32; ++kk) acc = fmaf(As[kk], wp[(size_t)kk * FDIM], acc);
    p.P[(size_t)s * FDIM + col] = acc;
  }
  gbar(bar, ++k);
  if (bx < 16) {
    const int col = bx * 256 + t;
    float v = 0.f;
    for (int s = 0; s < 32; ++s) v += p.P[(size_t)s * FDIM + col];
    p.g[col] = fmaxf(v + p.bf1[col], 0.f);
  }
  gbar(bar, ++k);

  // ---- gemv2: g @ Wf2 partials  (16 colgrps x 32 splits, Kt=128)
  { const int s = bx >> 4;
    const int k0 = s * 128;
    if (t < 128) As[t] = p.g[k0 + t];
    __syncthreads();
    const int col = (bx & 15) * 256 + t;
    const float* wp = p.Wf2 + (size_t)k0 * FDIM + col;
    float acc = 0.f;
    #pragma unroll 16
    for (int kk = 0; kk < 128; ++kk) acc = fmaf(As[kk], wp[(size_t)kk * FDIM], acc);
    p.P2[(size_t)s * FDIM + col] = acc;
  }
  gbar(bar, ++k);
  if (bx < 16) {
    const int col = bx * 256 + t;
    float v = 0.f;
    for (int s = 0; s < 32; ++s) v += p.P2[(size_t)s * FDIM + col];
    p.out[col] = v + p.bf2[col];
  }
}

// ---------------------------------------------------------------------------
extern "C" void kernel_launch(void* const* d_in, const int* in_sizes, int n_in,
                              void* d_out, int out_size, void* d_ws, size_t ws_size,
                              hipStream_t stream) {
  (void)in_sizes; (void)n_in; (void)out_size; (void)ws_size;
  float* ws = (float*)d_ws;

  Params p;
  p.q    = (const float*)d_in[0];   p.doc  = (const float*)d_in[1];
  p.Wp   = (const float*)d_in[2];   p.bp   = (const float*)d_in[3];
  p.Wqkv = (const float*)d_in[4];   p.bqkv = (const float*)d_in[5];
  p.Wo   = (const float*)d_in[6];   p.bo   = (const float*)d_in[7];
  p.ln1g = (const float*)d_in[8];   p.ln1b = (const float*)d_in[9];
  p.ln2g = (const float*)d_in[10];  p.ln2b = (const float*)d_in[11];
  p.W1   = (const float*)d_in[12];  p.b1   = (const float*)d_in[13];
  p.W2   = (const float*)d_in[14];  p.b2   = (const float*)d_in[15];
  p.Wa1  = (const float*)d_in[16];  p.ba1  = (const float*)d_in[17];
  p.Wa2  = (const float*)d_in[18];  p.ba2  = (const float*)d_in[19];
  p.Wf1  = (const float*)d_in[20];  p.bf1  = (const float*)d_in[21];
  p.Wf2  = (const float*)d_in[22];  p.bf2  = (const float*)d_in[23];
  p.out  = (float*)d_out;

  // workspace layout (float offsets)
  p.x      = ws;                   // 64x1024
  p.vbuf   = ws + 65536;           // 64x1024
  p.h      = ws + 131072;          // 64x4096
  p.P      = ws + 655360;          // 2M floats: gemm/gemv1 partials
  p.P2     = ws + 655360 + 262144; // 32x4096 gemv2 partials
  p.logits = ws + 2752512;         // 64
  p.fused  = ws + 2752576;         // 1024
  p.g      = ws + 2753600;         // 4096
  p.bar    = (int*)(ws + 2757696); // 640 ints (leaves/root/gen)

  (void)hipMemsetAsync(p.bar, 0, 4096, stream);
  mega_k<<<dim3(NGRID), dim3(256), 0, stream>>>(p);
}